// Round 3
// baseline (380.056 us; speedup 1.0000x reference)
//
#include <hip/hip_runtime.h>
#include <hip/hip_bf16.h>

#define NN 2048
#define BB 8
#define FD 256
#define NEG_SLOPE 0.2f
#define EPSV 1e-7f

typedef __bf16 bf16x8 __attribute__((ext_vector_type(8)));
typedef __bf16 bf16x4 __attribute__((ext_vector_type(4)));
typedef float f32x4 __attribute__((ext_vector_type(4)));

// async 16B global -> LDS (lds base wave-uniform; dest = base + lane*16)
__device__ __forceinline__ void gload16(const __bf16* g, __bf16* l) {
    __builtin_amdgcn_global_load_lds((const __attribute__((address_space(1))) unsigned int*)g,
                                     (__attribute__((address_space(3))) unsigned int*)l,
                                     16, 0, 0);
}

// ---------------- K1: WT[o][f] = bf16(W[f][o]) ----------------
__global__ __launch_bounds__(256) void k1_prep(const float* __restrict__ W,
                                               __bf16* __restrict__ WT) {
    int idx = blockIdx.x * 256 + threadIdx.x;   // 256 blocks
    int o = idx >> 8, f = idx & 255;
    WT[idx] = (__bf16)W[f * FD + o];
}

// ---------------- K2: Wh = x @ W (bf16 MFMA) + fused s_src/s_dst scores --------
__global__ __launch_bounds__(256) void k2_whgemm(const float* __restrict__ x,
                                                 const __bf16* __restrict__ WT,
                                                 const float* __restrict__ a_w,
                                                 float* __restrict__ Wh,
                                                 float* __restrict__ s_src,
                                                 float* __restrict__ s_dst) {
    const int wave = threadIdx.x >> 6;
    const int lane = threadIdx.x & 63;
    const int row0 = blockIdx.x * 32 + (wave >> 1) * 16;
    const int ohalf = (wave & 1) * 128;
    const int m = lane & 15;
    const int quad = lane >> 4;
    const int row = row0 + m;
    const float* xrow = x + (size_t)row * FD + quad * 8;

    f32x4 acc[8];
#pragma unroll
    for (int n = 0; n < 8; ++n) acc[n] = (f32x4){0.f, 0.f, 0.f, 0.f};

    for (int k0 = 0; k0 < FD; k0 += 32) {
        float4 xa = *(const float4*)(xrow + k0);
        float4 xb = *(const float4*)(xrow + k0 + 4);
        bf16x8 af;
        af[0] = (__bf16)xa.x; af[1] = (__bf16)xa.y; af[2] = (__bf16)xa.z; af[3] = (__bf16)xa.w;
        af[4] = (__bf16)xb.x; af[5] = (__bf16)xb.y; af[6] = (__bf16)xb.z; af[7] = (__bf16)xb.w;
#pragma unroll
        for (int n = 0; n < 8; ++n) {
            int o = ohalf + n * 16 + m;
            bf16x8 bf = *(const bf16x8*)(WT + o * FD + k0 + quad * 8);
            acc[n] = __builtin_amdgcn_mfma_f32_16x16x32_bf16(af, bf, acc[n], 0, 0, 0);
        }
    }
#pragma unroll
    for (int n = 0; n < 8; ++n) {
        int o = ohalf + n * 16 + m;
#pragma unroll
        for (int r = 0; r < 4; ++r) {
            Wh[(size_t)(row0 + quad * 4 + r) * FD + o] = acc[n][r];
        }
    }

    float psrc[4] = {0.f, 0.f, 0.f, 0.f};
    float pdst[4] = {0.f, 0.f, 0.f, 0.f};
#pragma unroll
    for (int n = 0; n < 8; ++n) {
        int o = ohalf + n * 16 + m;
        float awS = a_w[o], awD = a_w[FD + o];
#pragma unroll
        for (int r = 0; r < 4; ++r) {
            psrc[r] += acc[n][r] * awS;
            pdst[r] += acc[n][r] * awD;
        }
    }
#pragma unroll
    for (int off = 1; off <= 8; off <<= 1) {
#pragma unroll
        for (int r = 0; r < 4; ++r) {
            psrc[r] += __shfl_xor(psrc[r], off, 64);
            pdst[r] += __shfl_xor(pdst[r], off, 64);
        }
    }
    __shared__ float sS[2][2][16], sD[2][2][16];
    if (m == 0) {
        int rp = wave >> 1, oh = wave & 1;
#pragma unroll
        for (int r = 0; r < 4; ++r) {
            sS[rp][oh][quad * 4 + r] = psrc[r];
            sD[rp][oh][quad * 4 + r] = pdst[r];
        }
    }
    __syncthreads();
    if (threadIdx.x < 32) {
        int rp = threadIdx.x >> 4, idx = threadIdx.x & 15;
        int orow = blockIdx.x * 32 + rp * 16 + idx;
        s_src[orow] = sS[rp][0][idx] + sS[rp][1][idx];
        s_dst[orow] = sD[rp][0][idx] + sD[rp][1][idx];
    }
}

// ---------------- K4 (templated): den partials and/or P = A*exp(lrelu(e)) bf16 --
// b = blk & bmask, jhalf = (blk>>sh)&1, isp = blk>>(sh+1)  (32-row i-slab).
// WD: accumulate and store den partials. WP: store bf16 P tile.
template <bool WD, bool WP>
__global__ __launch_bounds__(256) void k4_t(const float* __restrict__ A,
                                            const float* __restrict__ s_src,
                                            const float* __restrict__ s_dst,
                                            const float* __restrict__ a_bp,
                                            float* __restrict__ den_part,
                                            __bf16* __restrict__ P,
                                            int bmask, int sh) {
    const int blk = blockIdx.x;
    const int b = blk & bmask;
    const int jhalf = (blk >> sh) & 1;
    const int isp = blk >> (sh + 1);
    const int i0 = isp * 32;
    const int j = jhalf * 1024 + threadIdx.x * 4;
    __shared__ float ss[32];
    if (threadIdx.x < 32) ss[threadIdx.x] = s_src[b * NN + i0 + threadIdx.x] + a_bp[0];
    __syncthreads();
    float4 sd = *(const float4*)(s_dst + b * NN + j);
    float ax = 0.f, ay = 0.f, az = 0.f, aw = 0.f;
    const float* Ap = A + ((size_t)b * NN + i0) * NN + j;
    __bf16* Pp = WP ? (P + ((size_t)b * NN + i0) * NN + j) : (__bf16*)0;
#pragma unroll 4
    for (int i = 0; i < 32; ++i) {
        float4 a = *(const float4*)(Ap + (size_t)i * NN);
        float si = ss[i];
        float e0 = si + sd.x; e0 = e0 > 0.f ? e0 : NEG_SLOPE * e0;
        float e1 = si + sd.y; e1 = e1 > 0.f ? e1 : NEG_SLOPE * e1;
        float e2 = si + sd.z; e2 = e2 > 0.f ? e2 : NEG_SLOPE * e2;
        float e3 = si + sd.w; e3 = e3 > 0.f ? e3 : NEG_SLOPE * e3;
        float p0 = a.x * __expf(e0);
        float p1 = a.y * __expf(e1);
        float p2 = a.z * __expf(e2);
        float p3 = a.w * __expf(e3);
        if (WD) { ax += p0; ay += p1; az += p2; aw += p3; }
        if (WP) {
            bf16x4 pv;
            pv[0] = (__bf16)p0; pv[1] = (__bf16)p1;
            pv[2] = (__bf16)p2; pv[3] = (__bf16)p3;
            *(bf16x4*)(Pp + (size_t)i * NN) = pv;
        }
    }
    if (WD) {
        float4 r = (float4){ax, ay, az, aw};
        *(float4*)(den_part + (size_t)isp * (BB * NN) + b * NN + j) = r;
    }
}

// ---------------- K5: WhT[b][o][j] = bf16( Wh[b][j][o] / (sum(den_part)+eps) ) ----
__global__ __launch_bounds__(256) void k5_wht(const float* __restrict__ Wh,
                                              const float* __restrict__ den_part,
                                              __bf16* __restrict__ WhT) {
    const int b = blockIdx.z;
    const int j0 = blockIdx.x * 64;
    const int o0 = blockIdx.y * 64;
    __shared__ float tile[64][65];
    __shared__ float invd[64];
    if (threadIdx.x < 64) {
        float s = 0.f;
        const float* dp = den_part + b * NN + j0 + threadIdx.x;
#pragma unroll 8
        for (int sI = 0; sI < 64; ++sI) s += dp[(size_t)sI * (BB * NN)];
        invd[threadIdx.x] = 1.f / (s + EPSV);
    }
    __syncthreads();
    int jr = threadIdx.x >> 4, oc = (threadIdx.x & 15) * 4;
#pragma unroll
    for (int p = 0; p < 4; ++p) {
        int jj = jr + p * 16;
        float4 v = *(const float4*)(Wh + (size_t)(b * NN + j0 + jj) * FD + o0 + oc);
        float s = invd[jj];
        tile[jj][oc + 0] = v.x * s;
        tile[jj][oc + 1] = v.y * s;
        tile[jj][oc + 2] = v.z * s;
        tile[jj][oc + 3] = v.w * s;
    }
    __syncthreads();
    int ow = threadIdx.x >> 4, jc = (threadIdx.x & 15) * 4;
#pragma unroll
    for (int p = 0; p < 4; ++p) {
        int o = ow + p * 16;
        bf16x4 wv;
        wv[0] = (__bf16)tile[jc + 0][o];
        wv[1] = (__bf16)tile[jc + 1][o];
        wv[2] = (__bf16)tile[jc + 2][o];
        wv[3] = (__bf16)tile[jc + 3][o];
        *(bf16x4*)(WhT + (size_t)(b * FD + o0 + o) * NN + j0 + jc) = wv;
    }
}

// ---------------- K6: pure bf16 GEMM: out[b] = P[b] @ WhT[b]^T ----------------
// Per b: M=2048, N=256, K=2048. Tile 64i x 128o, BK=64, double-buffered
// global_load_lds staging with XOR-swizzle (linear LDS dest + inverse-swizzled
// global source, swizzled ds_read — guide rule #21).
// b = blk & bmask, r_ = blk >> bsh: mt = r_&31, nh = r_>>5.
__global__ __launch_bounds__(256) void k6_gemm(const __bf16* __restrict__ P,
                                               const __bf16* __restrict__ WhT,
                                               float* __restrict__ out,
                                               int bmask, int bsh) {
    __shared__ __bf16 lA[2][64 * 64];    // 8 KiB x 2
    __shared__ __bf16 lB[2][128 * 64];   // 16 KiB x 2   (total 48 KiB)
    const int blk = blockIdx.x;
    const int b = blk & bmask;
    const int r_ = blk >> bsh;
    const int mt = r_ & 31;              // 32 M-tiles
    const int nh = r_ >> 5;              // 2 N-tiles
    const int i0 = mt * 64;
    const int o0 = nh * 128;
    const int t = threadIdx.x;
    const int w = t >> 6, lane = t & 63;
    const int m = lane & 15, quad = lane >> 4;
    const int wr = w >> 1, wc = w & 1;

    // Staging: per call, each wave stages 8 rows x 64 k (1 KiB). Lane l ->
    // row l>>3, dest 16B chunk l&7. Source chunk pre-swizzled so that a
    // swizzled READ (chunk ^ (row&7)) returns linear data.
    const int srow = lane >> 3;
    const int schunk = (lane & 7) ^ srow;        // row&7 == srow (8-row groups)
    const __bf16* gA = P + ((size_t)(b * NN + i0 + w * 8 + srow)) * NN + schunk * 8;
    const __bf16* gB = WhT + ((size_t)(b * FD + o0 + w * 8 + srow)) * NN + schunk * 8;

#define STAGE6(buf, step) { \
        const __bf16* ga = gA + (step) * 64; \
        const __bf16* gb = gB + (step) * 64; \
        gload16(ga,                   &lA[buf][0] + (w * 8) * 64); \
        gload16(ga + (size_t)32 * NN, &lA[buf][0] + (32 + w * 8) * 64); \
        gload16(gb,                   &lB[buf][0] + (w * 8) * 64); \
        gload16(gb + (size_t)32 * NN, &lB[buf][0] + (32 + w * 8) * 64); \
        gload16(gb + (size_t)64 * NN, &lB[buf][0] + (64 + w * 8) * 64); \
        gload16(gb + (size_t)96 * NN, &lB[buf][0] + (96 + w * 8) * 64); \
    }

    STAGE6(0, 0)

    f32x4 acc[2][4];
#pragma unroll
    for (int mi = 0; mi < 2; ++mi)
#pragma unroll
        for (int n = 0; n < 4; ++n) acc[mi][n] = (f32x4){0.f, 0.f, 0.f, 0.f};

    const int swz = (m & 7) * 8;   // XOR swizzle (element units; read rows: row&7 == m&7)
    for (int kt = 0; kt < 32; ++kt) {
        __syncthreads();           // buf (kt&1) fully staged; prev reads done
        const int cur = kt & 1, nb = cur ^ 1;
        if (kt < 31) STAGE6(nb, kt + 1)
        const __bf16* lAc = &lA[cur][0];
        const __bf16* lBc = &lB[cur][0];
#pragma unroll
        for (int ks = 0; ks < 2; ++ks) {
            const int kof = (ks * 32 + quad * 8) ^ swz;
            bf16x8 a0 = *(const bf16x8*)(lAc + (wr * 32 + m) * 64 + kof);
            bf16x8 a1 = *(const bf16x8*)(lAc + (wr * 32 + 16 + m) * 64 + kof);
#pragma unroll
            for (int n = 0; n < 4; ++n) {
                bf16x8 bfr = *(const bf16x8*)(lBc + (wc * 64 + n * 16 + m) * 64 + kof);
                acc[0][n] = __builtin_amdgcn_mfma_f32_16x16x32_bf16(a0, bfr, acc[0][n], 0, 0, 0);
                acc[1][n] = __builtin_amdgcn_mfma_f32_16x16x32_bf16(a1, bfr, acc[1][n], 0, 0, 0);
            }
        }
    }

#pragma unroll
    for (int mi = 0; mi < 2; ++mi)
#pragma unroll
        for (int n = 0; n < 4; ++n) {
            int o = o0 + wc * 64 + n * 16 + m;
#pragma unroll
            for (int rr = 0; rr < 4; ++rr) {
                int orow = i0 + wr * 32 + mi * 16 + quad * 4 + rr;
                out[((size_t)b * NN + orow) * FD + o] = acc[mi][n][rr];
            }
        }
#undef STAGE6
}

extern "C" void kernel_launch(void* const* d_in, const int* in_sizes, int n_in,
                              void* d_out, int out_size, void* d_ws, size_t ws_size,
                              hipStream_t stream) {
    const float* A   = (const float*)d_in[0];
    const float* x   = (const float*)d_in[1];
    const float* W   = (const float*)d_in[2];
    const float* a_w = (const float*)d_in[3];
    const float* a_b = (const float*)d_in[4];
    float* out = (float*)d_out;

    char* ws = (char*)d_ws;
    __bf16* WT      = (__bf16*)ws;                      // 131,072 B
    float*  Wh      = (float*)(ws + 131072);            // 16,777,216 B
    __bf16* WhT     = (__bf16*)(ws + 16908288);         // 8,388,608 B
    float*  s_src   = (float*)(ws + 25296896);          // 65,536 B
    float*  s_dst   = (float*)(ws + 25362432);          // 65,536 B
    float*  den_part= (float*)(ws + 25427968);          // 64*16384*4 = 4,194,304 B
                                                        // total = 29,622,272 B
                                                        // (same proven footprint as baseline)

    k1_prep<<<256, 256, 0, stream>>>(W, WT);
    k2_whgemm<<<512, 256, 0, stream>>>(x, WT, a_w, Wh, s_src, s_dst);

    // Pass 1: denominator partials over all batches (A read #1).
    // Valid dummy for the unused P arg (never written: WP=false).
    k4_t<true, false><<<1024, 256, 0, stream>>>(A, s_src, s_dst, a_b,
                                                den_part, WhT, 7, 3);
    // WhT = column-normalized Wh, transposed, bf16.
    k5_wht<<<dim3(32, 4, 8), 256, 0, stream>>>(Wh, den_part, WhT);

    // Pass 2: per 2-batch pair, rebuild P = A*exp(lrelu(e)) as bf16 into the
    // now-dead Wh region (exactly 2*2048*2048 bf16 = 16,777,216 B), then the
    // pure-bf16 GEMM out = P @ WhT^T for that pair. A read #2 (chunked).
    __bf16* Ppair = (__bf16*)Wh;
    for (int c = 0; c < 4; ++c) {
        const float* Ac  = A + (size_t)2 * c * NN * NN;
        const float* ssc = s_src + (size_t)2 * c * NN;
        const float* sdc = s_dst + (size_t)2 * c * NN;
        // Valid dummy for the unused den arg (never written: WD=false).
        k4_t<false, true><<<256, 256, 0, stream>>>(Ac, ssc, sdc, a_b,
                                                   den_part, Ppair, 1, 1);
        k6_gemm<<<128, 256, 0, stream>>>(Ppair,
                                         WhT + (size_t)2 * c * FD * NN,
                                         out + (size_t)2 * c * NN * FD, 1, 1);
    }
}

// Round 4
// 295.743 us; speedup vs baseline: 1.2851x; 1.2851x over previous
//
#include <hip/hip_runtime.h>
#include <hip/hip_bf16.h>

#define NN 2048
#define BB 8
#define FD 256
#define NEG_SLOPE 0.2f
#define EPSV 1e-7f

typedef __bf16 bf16x8 __attribute__((ext_vector_type(8)));
typedef __bf16 bf16x4 __attribute__((ext_vector_type(4)));
typedef float f32x4 __attribute__((ext_vector_type(4)));

// async 16B global -> LDS (lds base wave-uniform; dest = base + lane*16)
__device__ __forceinline__ void gload16(const __bf16* g, __bf16* l) {
    __builtin_amdgcn_global_load_lds((const __attribute__((address_space(1))) unsigned int*)g,
                                     (__attribute__((address_space(3))) unsigned int*)l,
                                     16, 0, 0);
}

// ---------------- K1: WT[o][f] = bf16(W[f][o]) ----------------
__global__ __launch_bounds__(256) void k1_prep(const float* __restrict__ W,
                                               __bf16* __restrict__ WT) {
    int idx = blockIdx.x * 256 + threadIdx.x;   // 256 blocks
    int o = idx >> 8, f = idx & 255;
    WT[idx] = (__bf16)W[f * FD + o];
}

// ---------------- K2: Wh = x @ W (bf16 MFMA) + fused s_src/s_dst scores --------
__global__ __launch_bounds__(256) void k2_whgemm(const float* __restrict__ x,
                                                 const __bf16* __restrict__ WT,
                                                 const float* __restrict__ a_w,
                                                 float* __restrict__ Wh,
                                                 float* __restrict__ s_src,
                                                 float* __restrict__ s_dst) {
    const int wave = threadIdx.x >> 6;
    const int lane = threadIdx.x & 63;
    const int row0 = blockIdx.x * 32 + (wave >> 1) * 16;
    const int ohalf = (wave & 1) * 128;
    const int m = lane & 15;
    const int quad = lane >> 4;
    const int row = row0 + m;
    const float* xrow = x + (size_t)row * FD + quad * 8;

    f32x4 acc[8];
#pragma unroll
    for (int n = 0; n < 8; ++n) acc[n] = (f32x4){0.f, 0.f, 0.f, 0.f};

    for (int k0 = 0; k0 < FD; k0 += 32) {
        float4 xa = *(const float4*)(xrow + k0);
        float4 xb = *(const float4*)(xrow + k0 + 4);
        bf16x8 af;
        af[0] = (__bf16)xa.x; af[1] = (__bf16)xa.y; af[2] = (__bf16)xa.z; af[3] = (__bf16)xa.w;
        af[4] = (__bf16)xb.x; af[5] = (__bf16)xb.y; af[6] = (__bf16)xb.z; af[7] = (__bf16)xb.w;
#pragma unroll
        for (int n = 0; n < 8; ++n) {
            int o = ohalf + n * 16 + m;
            bf16x8 bf = *(const bf16x8*)(WT + o * FD + k0 + quad * 8);
            acc[n] = __builtin_amdgcn_mfma_f32_16x16x32_bf16(af, bf, acc[n], 0, 0, 0);
        }
    }
#pragma unroll
    for (int n = 0; n < 8; ++n) {
        int o = ohalf + n * 16 + m;
#pragma unroll
        for (int r = 0; r < 4; ++r) {
            Wh[(size_t)(row0 + quad * 4 + r) * FD + o] = acc[n][r];
        }
    }

    float psrc[4] = {0.f, 0.f, 0.f, 0.f};
    float pdst[4] = {0.f, 0.f, 0.f, 0.f};
#pragma unroll
    for (int n = 0; n < 8; ++n) {
        int o = ohalf + n * 16 + m;
        float awS = a_w[o], awD = a_w[FD + o];
#pragma unroll
        for (int r = 0; r < 4; ++r) {
            psrc[r] += acc[n][r] * awS;
            pdst[r] += acc[n][r] * awD;
        }
    }
#pragma unroll
    for (int off = 1; off <= 8; off <<= 1) {
#pragma unroll
        for (int r = 0; r < 4; ++r) {
            psrc[r] += __shfl_xor(psrc[r], off, 64);
            pdst[r] += __shfl_xor(pdst[r], off, 64);
        }
    }
    __shared__ float sS[2][2][16], sD[2][2][16];
    if (m == 0) {
        int rp = wave >> 1, oh = wave & 1;
#pragma unroll
        for (int r = 0; r < 4; ++r) {
            sS[rp][oh][quad * 4 + r] = psrc[r];
            sD[rp][oh][quad * 4 + r] = pdst[r];
        }
    }
    __syncthreads();
    if (threadIdx.x < 32) {
        int rp = threadIdx.x >> 4, idx = threadIdx.x & 15;
        int orow = blockIdx.x * 32 + rp * 16 + idx;
        s_src[orow] = sS[rp][0][idx] + sS[rp][1][idx];
        s_dst[orow] = sD[rp][0][idx] + sD[rp][1][idx];
    }
}

// ---------------- K4: den_part[isp][b][j] = partial column sums ----------------
__global__ __launch_bounds__(256) void k4_den(const float* __restrict__ A,
                                              const float* __restrict__ s_src,
                                              const float* __restrict__ s_dst,
                                              const float* __restrict__ a_bp,
                                              float* __restrict__ den_part) {
    const int blk = blockIdx.x;
    const int b = blk & 7;
    const int jhalf = (blk >> 3) & 1;
    const int isp = blk >> 4;
    const int i0 = isp * 32;
    const int j = jhalf * 1024 + threadIdx.x * 4;
    __shared__ float ss[32];
    if (threadIdx.x < 32) ss[threadIdx.x] = s_src[b * NN + i0 + threadIdx.x] + a_bp[0];
    __syncthreads();
    float4 sd = *(const float4*)(s_dst + b * NN + j);
    float ax = 0.f, ay = 0.f, az = 0.f, aw = 0.f;
    const float* Ap = A + ((size_t)b * NN + i0) * NN + j;
#pragma unroll 8
    for (int i = 0; i < 32; ++i) {
        float4 a = *(const float4*)(Ap + (size_t)i * NN);
        float si = ss[i];
        float e0 = si + sd.x; e0 = e0 > 0.f ? e0 : NEG_SLOPE * e0;
        float e1 = si + sd.y; e1 = e1 > 0.f ? e1 : NEG_SLOPE * e1;
        float e2 = si + sd.z; e2 = e2 > 0.f ? e2 : NEG_SLOPE * e2;
        float e3 = si + sd.w; e3 = e3 > 0.f ? e3 : NEG_SLOPE * e3;
        ax += a.x * __expf(e0);
        ay += a.y * __expf(e1);
        az += a.z * __expf(e2);
        aw += a.w * __expf(e3);
    }
    float4 r = (float4){ax, ay, az, aw};
    *(float4*)(den_part + (size_t)isp * (BB * NN) + b * NN + j) = r;
}

// ---------------- K5: WhT[b][o][j] = bf16( Wh[b][j][o] / (sum(den_part)+eps) ) ----
__global__ __launch_bounds__(256) void k5_wht(const float* __restrict__ Wh,
                                              const float* __restrict__ den_part,
                                              __bf16* __restrict__ WhT) {
    const int b = blockIdx.z;
    const int j0 = blockIdx.x * 64;
    const int o0 = blockIdx.y * 64;
    __shared__ float tile[64][65];
    __shared__ float invd[64];
    if (threadIdx.x < 64) {
        float s = 0.f;
        const float* dp = den_part + b * NN + j0 + threadIdx.x;
#pragma unroll 8
        for (int sI = 0; sI < 64; ++sI) s += dp[(size_t)sI * (BB * NN)];
        invd[threadIdx.x] = 1.f / (s + EPSV);
    }
    __syncthreads();
    int jr = threadIdx.x >> 4, oc = (threadIdx.x & 15) * 4;
#pragma unroll
    for (int p = 0; p < 4; ++p) {
        int jj = jr + p * 16;
        float4 v = *(const float4*)(Wh + (size_t)(b * NN + j0 + jj) * FD + o0 + oc);
        float s = invd[jj];
        tile[jj][oc + 0] = v.x * s;
        tile[jj][oc + 1] = v.y * s;
        tile[jj][oc + 2] = v.z * s;
        tile[jj][oc + 3] = v.w * s;
    }
    __syncthreads();
    int ow = threadIdx.x >> 4, jc = (threadIdx.x & 15) * 4;
#pragma unroll
    for (int p = 0; p < 4; ++p) {
        int o = ow + p * 16;
        bf16x4 wv;
        wv[0] = (__bf16)tile[jc + 0][o];
        wv[1] = (__bf16)tile[jc + 1][o];
        wv[2] = (__bf16)tile[jc + 2][o];
        wv[3] = (__bf16)tile[jc + 3][o];
        *(bf16x4*)(WhT + (size_t)(b * FD + o0 + o) * NN + j0 + jc) = wv;
    }
}

// ---------------- K6F: fused out = (A*exp(lrelu(e))) @ WhTn^T, full grid -------
// Grid 512 (2 blocks/CU): b = blk&7 (XCD affinity; WhT[b]=1MB L2-resident),
// r_ = blk>>3: nh = r_&1 (o-half, adjacent-in-XCD for A L2 reuse), mt = r_>>1.
// Block: 64i x 128o, 4 waves (2x2), BK=64, K=2048 -> 32 steps.
// Per step: P-tile [64x64] built in regs from A f32 + scores -> bf16 LDS
// (XOR-swizzled); B-tile [128x64] via double-buffered global_load_lds
// (pre-swizzled source). 16 MFMA/wave/step. A-loads issued BEFORE the B
// staging so the P-build's waitcnt retires A while B stays in flight (T14).
__global__ __launch_bounds__(256) void k6f(const float* __restrict__ A,
                                           const __bf16* __restrict__ WhT,
                                           const float* __restrict__ s_src,
                                           const float* __restrict__ s_dst,
                                           const float* __restrict__ a_bp,
                                           float* __restrict__ out) {
    __shared__ __bf16 lP[2][64 * 64];     // 8 KiB x 2
    __shared__ __bf16 lB[2][128 * 64];    // 16 KiB x 2  (48 KiB total)
    const int blk = blockIdx.x;
    const int b = blk & 7;
    const int r_ = blk >> 3;
    const int nh = r_ & 1;
    const int mt = r_ >> 1;
    const int i0 = mt * 64;
    const int o0 = nh * 128;
    const int t = threadIdx.x;
    const int w = t >> 6, lane = t & 63;
    const int m = lane & 15, quad = lane >> 4;
    const int wr = w >> 1, wc = w & 1;

    // ---- B staging (same pattern that passed in round 3) ----
    const int srow = lane >> 3;
    const int schunk = (lane & 7) ^ srow;   // pre-swizzled source chunk
    const __bf16* gB = WhT + ((size_t)(b * FD + o0 + w * 8 + srow)) * NN + schunk * 8;

#define STAGEB(buf, step) { \
        const __bf16* gb = gB + (step) * 64; \
        gload16(gb,                   &lB[buf][0] + (w * 8) * 64); \
        gload16(gb + (size_t)32 * NN, &lB[buf][0] + (32 + w * 8) * 64); \
        gload16(gb + (size_t)64 * NN, &lB[buf][0] + (64 + w * 8) * 64); \
        gload16(gb + (size_t)96 * NN, &lB[buf][0] + (96 + w * 8) * 64); \
    }

    // ---- P-build role: row pr = t>>2 (0..63), col group pc = (t&3)*16 ----
    const int pr = t >> 2;
    const int pc = (t & 3) * 16;
    const float ssr = s_src[b * NN + i0 + pr] + a_bp[0];
    const float* Ap  = A + ((size_t)(b * NN + i0 + pr)) * NN + pc;
    const float* sdp = s_dst + b * NN + pc;
    // swizzled chunk positions (writer stores chunk ch at ch ^ (pr&7))
    const int ch0 = pc >> 3;                       // even
    const int sw0 = ((ch0    ) ^ (pr & 7)) * 8;
    const int sw1 = ((ch0 + 1) ^ (pr & 7)) * 8;
    __bf16* lProw = &lP[0][0] + pr * 64;

    float4 a0_, a1_, a2_, a3_, d0_, d1_, d2_, d3_;
#define LOADP(step) { \
        const float* ap = Ap  + (step) * 64; \
        const float* dp = sdp + (step) * 64; \
        a0_ = *(const float4*)(ap + 0);  a1_ = *(const float4*)(ap + 4); \
        a2_ = *(const float4*)(ap + 8);  a3_ = *(const float4*)(ap + 12); \
        d0_ = *(const float4*)(dp + 0);  d1_ = *(const float4*)(dp + 4); \
        d2_ = *(const float4*)(dp + 8);  d3_ = *(const float4*)(dp + 12); \
    }
#define PB1(vv, idx, av, dv) { \
        float e = ssr + dv; e = e > 0.f ? e : NEG_SLOPE * e; \
        vv[idx] = (__bf16)(av * __expf(e)); }
#define PBUILD(buf) { \
        bf16x8 v0, v1; \
        PB1(v0, 0, a0_.x, d0_.x) PB1(v0, 1, a0_.y, d0_.y) \
        PB1(v0, 2, a0_.z, d0_.z) PB1(v0, 3, a0_.w, d0_.w) \
        PB1(v0, 4, a1_.x, d1_.x) PB1(v0, 5, a1_.y, d1_.y) \
        PB1(v0, 6, a1_.z, d1_.z) PB1(v0, 7, a1_.w, d1_.w) \
        PB1(v1, 0, a2_.x, d2_.x) PB1(v1, 1, a2_.y, d2_.y) \
        PB1(v1, 2, a2_.z, d2_.z) PB1(v1, 3, a2_.w, d2_.w) \
        PB1(v1, 4, a3_.x, d3_.x) PB1(v1, 5, a3_.y, d3_.y) \
        PB1(v1, 6, a3_.z, d3_.z) PB1(v1, 7, a3_.w, d3_.w) \
        *(bf16x8*)(lProw + (buf) * 4096 + sw0) = v0; \
        *(bf16x8*)(lProw + (buf) * 4096 + sw1) = v1; \
    }

    // prologue: step-0 A regs, step-0 B staging, step-0 P build
    LOADP(0)
    STAGEB(0, 0)
    PBUILD(0)

    f32x4 acc[2][4];
#pragma unroll
    for (int mi = 0; mi < 2; ++mi)
#pragma unroll
        for (int n = 0; n < 4; ++n) acc[mi][n] = (f32x4){0.f, 0.f, 0.f, 0.f};

    const int swz = (m & 7) * 8;   // MFMA-read XOR swizzle (row&7 == m&7)
    for (int kt = 0; kt < 32; ++kt) {
        __syncthreads();           // lP[cur] + lB[cur] fully staged; prev reads done
        const int cur = kt & 1, nb = cur ^ 1;
        if (kt < 31) {
            LOADP(kt + 1)          // A/sd regs first (older in vmcnt queue)
            STAGEB(nb, kt + 1)     // B gloads after (stay in flight past A-wait)
        }
        const __bf16* lPc = &lP[cur][0];
        const __bf16* lBc = &lB[cur][0];
#pragma unroll
        for (int ks = 0; ks < 2; ++ks) {
            const int kof = (ks * 32 + quad * 8) ^ swz;
            bf16x8 pa0 = *(const bf16x8*)(lPc + (wr * 32 + m) * 64 + kof);
            bf16x8 pa1 = *(const bf16x8*)(lPc + (wr * 32 + 16 + m) * 64 + kof);
#pragma unroll
            for (int n = 0; n < 4; ++n) {
                bf16x8 bfr = *(const bf16x8*)(lBc + (wc * 64 + n * 16 + m) * 64 + kof);
                acc[0][n] = __builtin_amdgcn_mfma_f32_16x16x32_bf16(pa0, bfr, acc[0][n], 0, 0, 0);
                acc[1][n] = __builtin_amdgcn_mfma_f32_16x16x32_bf16(pa1, bfr, acc[1][n], 0, 0, 0);
            }
        }
        if (kt < 31) PBUILD(nb)
    }

#pragma unroll
    for (int mi = 0; mi < 2; ++mi)
#pragma unroll
        for (int n = 0; n < 4; ++n) {
            int o = o0 + wc * 64 + n * 16 + m;
#pragma unroll
            for (int rr = 0; rr < 4; ++rr) {
                int orow = i0 + wr * 32 + mi * 16 + quad * 4 + rr;
                out[((size_t)b * NN + orow) * FD + o] = acc[mi][n][rr];
            }
        }
#undef STAGEB
#undef LOADP
#undef PB1
#undef PBUILD
}

extern "C" void kernel_launch(void* const* d_in, const int* in_sizes, int n_in,
                              void* d_out, int out_size, void* d_ws, size_t ws_size,
                              hipStream_t stream) {
    const float* A   = (const float*)d_in[0];
    const float* x   = (const float*)d_in[1];
    const float* W   = (const float*)d_in[2];
    const float* a_w = (const float*)d_in[3];
    const float* a_b = (const float*)d_in[4];
    float* out = (float*)d_out;

    char* ws = (char*)d_ws;
    __bf16* WT      = (__bf16*)ws;                      // 131,072 B
    float*  Wh      = (float*)(ws + 131072);            // 16,777,216 B
    __bf16* WhT     = (__bf16*)(ws + 16908288);         // 8,388,608 B
    float*  s_src   = (float*)(ws + 25296896);          // 65,536 B
    float*  s_dst   = (float*)(ws + 25362432);          // 65,536 B
    float*  den_part= (float*)(ws + 25427968);          // 64*16384*4 = 4,194,304 B
                                                        // total = 29,622,272 B
                                                        // (proven baseline footprint)

    k1_prep<<<256, 256, 0, stream>>>(W, WT);
    k2_whgemm<<<512, 256, 0, stream>>>(x, WT, a_w, Wh, s_src, s_dst);
    k4_den<<<1024, 256, 0, stream>>>(A, s_src, s_dst, a_b, den_part);
    k5_wht<<<dim3(32, 4, 8), 256, 0, stream>>>(Wh, den_part, WhT);
    k6f<<<512, 256, 0, stream>>>(A, WhT, s_src, s_dst, a_b, out);
}